// Round 2
// baseline (703.713 us; speedup 1.0000x reference)
//
#include <hip/hip_runtime.h>
#include <stdint.h>

#define NTOK 16384
#define DIM  1024
#define ODIM 1024
#define NEXP 8

typedef float  f32x4  __attribute__((ext_vector_type(4)));
typedef __bf16 bf16x8 __attribute__((ext_vector_type(8)));
typedef short  s16x8  __attribute__((ext_vector_type(8)));

__device__ __forceinline__ uint16_t f2bf(float f) {
  uint32_t u = __builtin_bit_cast(uint32_t, f);
  u += 0x7fffu + ((u >> 16) & 1u);
  return (uint16_t)(u >> 16);
}

__device__ __forceinline__ void gload_lds16(const void* g, void* l) {
  __builtin_amdgcn_global_load_lds(
      (const __attribute__((address_space(1))) uint32_t*)g,
      (__attribute__((address_space(3))) uint32_t*)l, 16, 0, 0);
}

// ---------------- Kernel 1: gate (fp32) + route + x -> bf16 ----------------
// One token per wave, 4 waves/block, 4096 blocks. No LDS; gate_w (32 KB) is
// L1-resident and read per-lane as float4. x read as float4, xb written as
// ushort4. One 64-lane butterfly reduce of 8 partial sums per token.
__global__ __launch_bounds__(256) void gate_kernel(
    const float* __restrict__ x, const float* __restrict__ gate_w,
    const float* __restrict__ gate_b, uint16_t* __restrict__ xb,
    int* __restrict__ cnt0, int* __restrict__ cnt1,
    int* __restrict__ tok0, int* __restrict__ tok1,
    float* __restrict__ pr0, float* __restrict__ pr1) {
  const int tid = threadIdx.x;
  const int wave = tid >> 6, lane = tid & 63;
  const int n = blockIdx.x * 4 + wave;

  float s[8] = {0.f, 0.f, 0.f, 0.f, 0.f, 0.f, 0.f, 0.f};
#pragma unroll
  for (int it = 0; it < 4; ++it) {
    const int d = it * 256 + lane * 4;
    const f32x4 xv = *reinterpret_cast<const f32x4*>(&x[(size_t)n * DIM + d]);
    ushort4 ob;
    ob.x = f2bf(xv[0]); ob.y = f2bf(xv[1]);
    ob.z = f2bf(xv[2]); ob.w = f2bf(xv[3]);
    *reinterpret_cast<ushort4*>(&xb[(size_t)n * DIM + d]) = ob;
#pragma unroll
    for (int dd = 0; dd < 4; ++dd) {
      const f32x4 w0 = *reinterpret_cast<const f32x4*>(&gate_w[(size_t)(d + dd) * 8]);
      const f32x4 w1 = *reinterpret_cast<const f32x4*>(&gate_w[(size_t)(d + dd) * 8 + 4]);
      s[0] += xv[dd] * w0[0]; s[1] += xv[dd] * w0[1];
      s[2] += xv[dd] * w0[2]; s[3] += xv[dd] * w0[3];
      s[4] += xv[dd] * w1[0]; s[5] += xv[dd] * w1[1];
      s[6] += xv[dd] * w1[2]; s[7] += xv[dd] * w1[3];
    }
  }
#pragma unroll
  for (int e = 0; e < 8; ++e) {
    float v = s[e];
    for (int m = 1; m < 64; m <<= 1) v += __shfl_xor(v, m);
    s[e] = v + gate_b[e];
  }
  if (lane == 0) {
    // top-2 (strict > keeps lowest index on ties, matches lax.top_k)
    float v1 = -1e30f; int i1 = 0;
#pragma unroll
    for (int e = 0; e < 8; ++e) if (s[e] > v1) { v1 = s[e]; i1 = e; }
    float v2 = -1e30f; int i2 = -1;
#pragma unroll
    for (int e = 0; e < 8; ++e) if (e != i1 && s[e] > v2) { v2 = s[e]; i2 = e; }
    float ssum = 0.f;
#pragma unroll
    for (int e = 0; e < 8; ++e) ssum += expf(s[e] - v1);
    const float p1 = 1.0f / ssum;  // expf(v1-v1)=1
    const float p2 = expf(v2 - v1) / ssum;
    int pos0 = atomicAdd(&cnt0[i1], 1);
    tok0[i1 * NTOK + pos0] = n;  pr0[i1 * NTOK + pos0] = p1;
    int pos1 = atomicAdd(&cnt1[i2], 1);
    tok1[i2 * NTOK + pos1] = n;  pr1[i2 * NTOK + pos1] = p2;
  }
}

// ------------- Kernel 2: expert_w [E][D][O] fp32 -> wt [E][O][D] bf16 -------------
__global__ __launch_bounds__(256) void wcast_kernel(
    const float* __restrict__ ew, uint16_t* __restrict__ wt) {
  __shared__ uint16_t tile[64][65];
  const int e = blockIdx.z;
  const int db = blockIdx.y * 64, ob = blockIdx.x * 64;
  const int t = threadIdx.x, c = t & 63, r4 = t >> 6;
#pragma unroll
  for (int i = 0; i < 16; ++i) {
    int d = db + i * 4 + r4;
    tile[i * 4 + r4][c] = f2bf(ew[((size_t)e * DIM + d) * ODIM + ob + c]);
  }
  __syncthreads();
#pragma unroll
  for (int i = 0; i < 16; ++i) {
    int o = ob + i * 4 + r4;
    wt[((size_t)e * ODIM + o) * DIM + db + c] = tile[c][i * 4 + r4];
  }
}

// ---------------- Kernel 3: grouped GEMM, 128x128x32 bf16 MFMA ----------------
// pass ACCUM=0: out[tok] = p*(x@W+b) ; ACCUM=1: out[tok] += p*(x@W+b)
template <int ACCUM>
__global__ __launch_bounds__(256) void moe_gemm(
    const uint16_t* __restrict__ xb, const uint16_t* __restrict__ wt,
    const float* __restrict__ eb, const int* __restrict__ cnt,
    const int* __restrict__ tok, const float* __restrict__ pr,
    float* __restrict__ out) {
  __shared__ __align__(16) uint16_t sA[128 * 32];
  __shared__ __align__(16) uint16_t sB[128 * 32];
  __shared__ int   tokl[128];
  __shared__ float pl[128];

  // map blockIdx.y -> (expert, m-block) via counts
  const int by = blockIdx.y;
  int e_sel = -1, m0 = 0, cnt_e = 0, run = 0;
#pragma unroll
  for (int e = 0; e < 8; ++e) {
    int c = cnt[e];
    int nb = (c + 127) >> 7;
    if (e_sel < 0 && by < run + nb) { e_sel = e; m0 = (by - run) << 7; cnt_e = c; }
    run += nb;
  }
  if (e_sel < 0) return;
  const int n0  = blockIdx.x * 128;
  const int tid = threadIdx.x;

  if (tid < 128) {
    int idx = m0 + tid;
    int valid = idx < cnt_e;
    tokl[tid] = valid ? tok[e_sel * NTOK + idx] : 0;
    pl[tid]   = valid ? pr[e_sel * NTOK + idx] : 0.f;
  }
  __syncthreads();

  const int wave = tid >> 6, lane = tid & 63;
  const int kc8 = (tid & 3) * 8;
  const uint16_t* srcA0 = xb + (size_t)tokl[tid >> 2] * DIM + kc8;
  const uint16_t* srcA1 = xb + (size_t)tokl[64 + (tid >> 2)] * DIM + kc8;
  const uint16_t* srcB0 = wt + ((size_t)e_sel * ODIM + n0 + (tid >> 2)) * DIM + kc8;
  const uint16_t* srcB1 = srcB0 + (size_t)64 * DIM;
  char* ldsA0 = (char*)sA + wave * 1024;
  char* ldsA1 = (char*)sA + 4096 + wave * 1024;
  char* ldsB0 = (char*)sB + wave * 1024;
  char* ldsB1 = (char*)sB + 4096 + wave * 1024;

  f32x4 acc[4][4] = {};
  const int wm = (wave & 1) * 64, wn = (wave >> 1) * 64;
  const int ro = lane >> 4, cl = lane & 15;

  for (int k0 = 0; k0 < DIM; k0 += 32) {
    gload_lds16(srcA0, ldsA0);
    gload_lds16(srcA1, ldsA1);
    gload_lds16(srcB0, ldsB0);
    gload_lds16(srcB1, ldsB1);
    srcA0 += 32; srcA1 += 32; srcB0 += 32; srcB1 += 32;
    __syncthreads();   // vmcnt(0) drain -> LDS tiles ready

    s16x8 a_[4], b_[4];
#pragma unroll
    for (int m = 0; m < 4; ++m)
      a_[m] = *reinterpret_cast<const s16x8*>(&sA[(wm + m * 16 + cl) * 32 + ro * 8]);
#pragma unroll
    for (int n = 0; n < 4; ++n)
      b_[n] = *reinterpret_cast<const s16x8*>(&sB[(wn + n * 16 + cl) * 32 + ro * 8]);
#pragma unroll
    for (int m = 0; m < 4; ++m)
#pragma unroll
      for (int n = 0; n < 4; ++n)
        acc[m][n] = __builtin_amdgcn_mfma_f32_16x16x32_bf16(
            __builtin_bit_cast(bf16x8, a_[m]), __builtin_bit_cast(bf16x8, b_[n]),
            acc[m][n], 0, 0, 0);
    __syncthreads();   // protect LDS before next stage
  }

  // epilogue: D row = ro*4+i, col = cl (m89-verified C/D layout)
#pragma unroll
  for (int n = 0; n < 4; ++n) {
    const int col = n0 + wn + n * 16 + cl;
    const float bias = eb[e_sel * ODIM + col];
#pragma unroll
    for (int m = 0; m < 4; ++m) {
#pragma unroll
      for (int i = 0; i < 4; ++i) {
        const int rl = wm + m * 16 + ro * 4 + i;
        if (m0 + rl < cnt_e) {
          const float v = pl[rl] * (acc[m][n][i] + bias);
          const size_t oidx = (size_t)tokl[rl] * ODIM + col;
          if (ACCUM) out[oidx] += v; else out[oidx] = v;
        }
      }
    }
  }
}

// ------------------------------- launcher -------------------------------
extern "C" void kernel_launch(void* const* d_in, const int* in_sizes, int n_in,
                              void* d_out, int out_size, void* d_ws, size_t ws_size,
                              hipStream_t stream) {
  const float* x      = (const float*)d_in[0];
  const float* gate_w = (const float*)d_in[1];
  const float* gate_b = (const float*)d_in[2];
  const float* ew     = (const float*)d_in[3];
  const float* eb     = (const float*)d_in[4];
  float* out = (float*)d_out;

  char* ws = (char*)d_ws;
  size_t off = 0;
  uint16_t* xb = (uint16_t*)(ws + off); off += (size_t)NTOK * DIM * 2;       // 32 MB
  uint16_t* wt = (uint16_t*)(ws + off); off += (size_t)NEXP * DIM * ODIM * 2; // 16 MB
  int*   tok0 = (int*)(ws + off);   off += (size_t)NEXP * NTOK * 4;
  int*   tok1 = (int*)(ws + off);   off += (size_t)NEXP * NTOK * 4;
  float* pr0  = (float*)(ws + off); off += (size_t)NEXP * NTOK * 4;
  float* pr1  = (float*)(ws + off); off += (size_t)NEXP * NTOK * 4;
  int*   cnt0 = (int*)(ws + off);   off += 32;
  int*   cnt1 = (int*)(ws + off);   off += 32;

  hipMemsetAsync(cnt0, 0, 64, stream);  // zeros cnt0[8] + cnt1[8]

  gate_kernel<<<NTOK / 4, 256, 0, stream>>>(x, gate_w, gate_b, xb,
                                            cnt0, cnt1, tok0, tok1, pr0, pr1);
  wcast_kernel<<<dim3(16, 16, 8), 256, 0, stream>>>(ew, wt);
  moe_gemm<0><<<dim3(8, 136), 256, 0, stream>>>(xb, wt, eb, cnt0, tok0, pr0, out);
  moe_gemm<1><<<dim3(8, 136), 256, 0, stream>>>(xb, wt, eb, cnt1, tok1, pr1, out);
}

// Round 5
// 410.838 us; speedup vs baseline: 1.7129x; 1.7129x over previous
//
#include <hip/hip_runtime.h>
#include <stdint.h>

#define NTOK 16384
#define DIM  1024
#define ODIM 1024
#define NEXP 8
#define CSTRIDE 16   // counters padded to 64B: one cache line each, no false sharing

typedef float  f32x4  __attribute__((ext_vector_type(4)));
typedef __bf16 bf16x8 __attribute__((ext_vector_type(8)));
typedef short  s16x8  __attribute__((ext_vector_type(8)));

__device__ __forceinline__ uint16_t f2bf(float f) {
  uint32_t u = __builtin_bit_cast(uint32_t, f);
  u += 0x7fffu + ((u >> 16) & 1u);
  return (uint16_t)(u >> 16);
}

__device__ __forceinline__ void gload_lds16(const void* g, void* l) {
  __builtin_amdgcn_global_load_lds(
      (const __attribute__((address_space(1))) uint32_t*)g,
      (__attribute__((address_space(3))) uint32_t*)l, 16, 0, 0);
}

// ---------------- Kernel 1: gate (fp32) + x -> bf16. NO ATOMICS. ----------------
// One token per wave; writes packed top-2 (e0|e1<<8) + probs by token index.
__global__ __launch_bounds__(256) void gate_kernel(
    const float* __restrict__ x, const float* __restrict__ gate_w,
    const float* __restrict__ gate_b, uint16_t* __restrict__ xb,
    int* __restrict__ e01, float* __restrict__ p0a, float* __restrict__ p1a) {
  const int tid = threadIdx.x;
  const int wave = tid >> 6, lane = tid & 63;
  const int n = blockIdx.x * 4 + wave;

  float s[8] = {0.f, 0.f, 0.f, 0.f, 0.f, 0.f, 0.f, 0.f};
#pragma unroll
  for (int it = 0; it < 4; ++it) {
    const int d = it * 256 + lane * 4;
    const f32x4 xv = *reinterpret_cast<const f32x4*>(&x[(size_t)n * DIM + d]);
    ushort4 ob;
    ob.x = f2bf(xv[0]); ob.y = f2bf(xv[1]);
    ob.z = f2bf(xv[2]); ob.w = f2bf(xv[3]);
    *reinterpret_cast<ushort4*>(&xb[(size_t)n * DIM + d]) = ob;
#pragma unroll
    for (int dd = 0; dd < 4; ++dd) {
      const f32x4 w0 = *reinterpret_cast<const f32x4*>(&gate_w[(size_t)(d + dd) * 8]);
      const f32x4 w1 = *reinterpret_cast<const f32x4*>(&gate_w[(size_t)(d + dd) * 8 + 4]);
      s[0] += xv[dd] * w0[0]; s[1] += xv[dd] * w0[1];
      s[2] += xv[dd] * w0[2]; s[3] += xv[dd] * w0[3];
      s[4] += xv[dd] * w1[0]; s[5] += xv[dd] * w1[1];
      s[6] += xv[dd] * w1[2]; s[7] += xv[dd] * w1[3];
    }
  }
#pragma unroll
  for (int e = 0; e < 8; ++e) {
    float v = s[e];
    for (int m = 1; m < 64; m <<= 1) v += __shfl_xor(v, m);
    s[e] = v + gate_b[e];
  }
  if (lane == 0) {
    // top-2 (strict > keeps lowest index on ties, matches lax.top_k)
    float v1 = -1e30f; int i1 = 0;
#pragma unroll
    for (int e = 0; e < 8; ++e) if (s[e] > v1) { v1 = s[e]; i1 = e; }
    float v2 = -1e30f; int i2 = -1;
#pragma unroll
    for (int e = 0; e < 8; ++e) if (e != i1 && s[e] > v2) { v2 = s[e]; i2 = e; }
    float ssum = 0.f;
#pragma unroll
    for (int e = 0; e < 8; ++e) ssum += expf(s[e] - v1);
    e01[n] = i1 | (i2 << 8);
    p0a[n] = 1.0f / ssum;            // expf(v1-v1)=1
    p1a[n] = expf(v2 - v1) / ssum;
  }
}

// -------- Kernel 1b: route — ballot-aggregated compaction, 1 atomic/wave/expert --------
__global__ __launch_bounds__(256) void route_kernel(
    const int* __restrict__ e01, const float* __restrict__ p0a,
    const float* __restrict__ p1a,
    int* __restrict__ cnt0, int* __restrict__ cnt1,
    int* __restrict__ tok0, int* __restrict__ tok1,
    float* __restrict__ pr0, float* __restrict__ pr1) {
  const int n = blockIdx.x * 256 + threadIdx.x;
  const int lane = threadIdx.x & 63;
  const int my = e01[n];
  const int e0 = my & 255, e1 = my >> 8;
  // lanes strictly below me; 1ull<<lane is defined for lane 0..63 (bug fix vs R4:
  // the old lane==63 special case used ~0ull which INCLUDED self -> poison slot -> GPU fault)
  const unsigned long long ltmask = (1ull << lane) - 1ull;
#pragma unroll
  for (int e = 0; e < NEXP; ++e) {
    unsigned long long m0 = __ballot(e0 == e);
    if (m0) {
      const int leader = __ffsll((long long)m0) - 1;
      int base = 0;
      if (lane == leader) base = atomicAdd(&cnt0[e * CSTRIDE], __popcll(m0));
      base = __shfl(base, leader);
      if (e0 == e) {
        const int slot = base + __popcll(m0 & ltmask);
        tok0[e * NTOK + slot] = n;  pr0[e * NTOK + slot] = p0a[n];
      }
    }
    unsigned long long m1 = __ballot(e1 == e);
    if (m1) {
      const int leader = __ffsll((long long)m1) - 1;
      int base = 0;
      if (lane == leader) base = atomicAdd(&cnt1[e * CSTRIDE], __popcll(m1));
      base = __shfl(base, leader);
      if (e1 == e) {
        const int slot = base + __popcll(m1 & ltmask);
        tok1[e * NTOK + slot] = n;  pr1[e * NTOK + slot] = p1a[n];
      }
    }
  }
}

// ------------- Kernel 2: expert_w [E][D][O] fp32 -> wt [E][O][D] bf16 -------------
__global__ __launch_bounds__(256) void wcast_kernel(
    const float* __restrict__ ew, uint16_t* __restrict__ wt) {
  __shared__ uint16_t tile[64][65];
  const int e = blockIdx.z;
  const int db = blockIdx.y * 64, ob = blockIdx.x * 64;
  const int t = threadIdx.x, c = t & 63, r4 = t >> 6;
#pragma unroll
  for (int i = 0; i < 16; ++i) {
    int d = db + i * 4 + r4;
    tile[i * 4 + r4][c] = f2bf(ew[((size_t)e * DIM + d) * ODIM + ob + c]);
  }
  __syncthreads();
#pragma unroll
  for (int i = 0; i < 16; ++i) {
    int o = ob + i * 4 + r4;
    wt[((size_t)e * ODIM + o) * DIM + db + c] = tile[c][i * 4 + r4];
  }
}

// ---------------- Kernel 3: grouped GEMM, 128x128x32 bf16 MFMA ----------------
// Double-buffered LDS, single barrier per K-step (T3 minimum-2-phase template).
// pass ACCUM=0: out[tok] = p*(x@W+b) ; ACCUM=1: out[tok] += p*(x@W+b)
template <int ACCUM>
__global__ __launch_bounds__(256) void moe_gemm(
    const uint16_t* __restrict__ xb, const uint16_t* __restrict__ wt,
    const float* __restrict__ eb, const int* __restrict__ cnt,
    const int* __restrict__ tok, const float* __restrict__ pr,
    float* __restrict__ out) {
  __shared__ __align__(16) uint16_t sA[2][128 * 32];
  __shared__ __align__(16) uint16_t sB[2][128 * 32];
  __shared__ int   tokl[128];
  __shared__ float pl[128];

  // map blockIdx.y -> (expert, m-block) via counts
  const int by = blockIdx.y;
  int e_sel = -1, m0 = 0, cnt_e = 0, run = 0;
#pragma unroll
  for (int e = 0; e < 8; ++e) {
    int c = cnt[e * CSTRIDE];
    int nb = (c + 127) >> 7;
    if (e_sel < 0 && by < run + nb) { e_sel = e; m0 = (by - run) << 7; cnt_e = c; }
    run += nb;
  }
  if (e_sel < 0) return;
  const int n0  = blockIdx.x * 128;
  const int tid = threadIdx.x;

  if (tid < 128) {
    int idx = m0 + tid;
    int valid = idx < cnt_e;
    tokl[tid] = valid ? tok[e_sel * NTOK + idx] : 0;
    pl[tid]   = valid ? pr[e_sel * NTOK + idx] : 0.f;
  }
  __syncthreads();

  const int wave = tid >> 6, lane = tid & 63;
  const int kc8 = (tid & 3) * 8;
  const uint16_t* srcA0 = xb + (size_t)tokl[tid >> 2] * DIM + kc8;
  const uint16_t* srcA1 = xb + (size_t)tokl[64 + (tid >> 2)] * DIM + kc8;
  const uint16_t* srcB0 = wt + ((size_t)e_sel * ODIM + n0 + (tid >> 2)) * DIM + kc8;
  const uint16_t* srcB1 = srcB0 + (size_t)64 * DIM;

  f32x4 acc[4][4] = {};
  const int wm = (wave & 1) * 64, wn = (wave >> 1) * 64;
  const int ro = lane >> 4, cl = lane & 15;

  // prologue: stage K-tile 0 into buffer 0
  {
    char* a = (char*)sA[0] + wave * 1024;
    char* b = (char*)sB[0] + wave * 1024;
    gload_lds16(srcA0, a);
    gload_lds16(srcA1, a + 4096);
    gload_lds16(srcB0, b);
    gload_lds16(srcB1, b + 4096);
    srcA0 += 32; srcA1 += 32; srcB0 += 32; srcB1 += 32;
  }
  __syncthreads();   // buffer 0 ready

  int cur = 0;
  for (int k0 = 0; k0 < DIM; k0 += 32) {
    if (k0 + 32 < DIM) {               // stage next tile into the other buffer
      char* a = (char*)sA[cur ^ 1] + wave * 1024;
      char* b = (char*)sB[cur ^ 1] + wave * 1024;
      gload_lds16(srcA0, a);
      gload_lds16(srcA1, a + 4096);
      gload_lds16(srcB0, b);
      gload_lds16(srcB1, b + 4096);
      srcA0 += 32; srcA1 += 32; srcB0 += 32; srcB1 += 32;
    }

    const uint16_t* cA = sA[cur];
    const uint16_t* cB = sB[cur];
    s16x8 a_[4], b_[4];
#pragma unroll
    for (int m = 0; m < 4; ++m)
      a_[m] = *reinterpret_cast<const s16x8*>(&cA[(wm + m * 16 + cl) * 32 + ro * 8]);
#pragma unroll
    for (int n = 0; n < 4; ++n)
      b_[n] = *reinterpret_cast<const s16x8*>(&cB[(wn + n * 16 + cl) * 32 + ro * 8]);
#pragma unroll
    for (int m = 0; m < 4; ++m)
#pragma unroll
      for (int n = 0; n < 4; ++n)
        acc[m][n] = __builtin_amdgcn_mfma_f32_16x16x32_bf16(
            __builtin_bit_cast(bf16x8, a_[m]), __builtin_bit_cast(bf16x8, b_[n]),
            acc[m][n], 0, 0, 0);

    __syncthreads();   // drains next-stage loads (vmcnt) + protects buffers
    cur ^= 1;
  }

  // epilogue: D row = ro*4+i, col = cl (m89-verified C/D layout)
#pragma unroll
  for (int n = 0; n < 4; ++n) {
    const int col = n0 + wn + n * 16 + cl;
    const float bias = eb[e_sel * ODIM + col];
#pragma unroll
    for (int m = 0; m < 4; ++m) {
#pragma unroll
      for (int i = 0; i < 4; ++i) {
        const int rl = wm + m * 16 + ro * 4 + i;
        if (m0 + rl < cnt_e) {
          const float v = pl[rl] * (acc[m][n][i] + bias);
          const size_t oidx = (size_t)tokl[rl] * ODIM + col;
          if (ACCUM) out[oidx] += v; else out[oidx] = v;
        }
      }
    }
  }
}

// ------------------------------- launcher -------------------------------
extern "C" void kernel_launch(void* const* d_in, const int* in_sizes, int n_in,
                              void* d_out, int out_size, void* d_ws, size_t ws_size,
                              hipStream_t stream) {
  const float* x      = (const float*)d_in[0];
  const float* gate_w = (const float*)d_in[1];
  const float* gate_b = (const float*)d_in[2];
  const float* ew     = (const float*)d_in[3];
  const float* eb     = (const float*)d_in[4];
  float* out = (float*)d_out;

  char* ws = (char*)d_ws;
  size_t off = 0;
  uint16_t* xb = (uint16_t*)(ws + off); off += (size_t)NTOK * DIM * 2;        // 32 MB
  uint16_t* wt = (uint16_t*)(ws + off); off += (size_t)NEXP * DIM * ODIM * 2; // 16 MB
  int*   tok0 = (int*)(ws + off);   off += (size_t)NEXP * NTOK * 4;
  int*   tok1 = (int*)(ws + off);   off += (size_t)NEXP * NTOK * 4;
  float* pr0  = (float*)(ws + off); off += (size_t)NEXP * NTOK * 4;
  float* pr1  = (float*)(ws + off); off += (size_t)NEXP * NTOK * 4;
  int*   e01  = (int*)(ws + off);   off += (size_t)NTOK * 4;
  float* p0a  = (float*)(ws + off); off += (size_t)NTOK * 4;
  float* p1a  = (float*)(ws + off); off += (size_t)NTOK * 4;
  int*   cnt0 = (int*)(ws + off);   off += NEXP * CSTRIDE * 4;
  int*   cnt1 = (int*)(ws + off);   off += NEXP * CSTRIDE * 4;

  hipMemsetAsync(cnt0, 0, 2 * NEXP * CSTRIDE * 4, stream);  // cnt0 + cnt1 (adjacent)

  gate_kernel<<<NTOK / 4, 256, 0, stream>>>(x, gate_w, gate_b, xb, e01, p0a, p1a);
  route_kernel<<<NTOK / 256, 256, 0, stream>>>(e01, p0a, p1a,
                                               cnt0, cnt1, tok0, tok1, pr0, pr1);
  wcast_kernel<<<dim3(16, 16, 8), 256, 0, stream>>>(ew, wt);
  moe_gemm<0><<<dim3(8, 136), 256, 0, stream>>>(xb, wt, eb, cnt0, tok0, pr0, out);
  moe_gemm<1><<<dim3(8, 136), 256, 0, stream>>>(xb, wt, eb, cnt1, tok1, pr1, out);
}